// Round 1
// baseline (167.957 us; speedup 1.0000x reference)
//
#include <hip/hip_runtime.h>
#include <hip/hip_bf16.h>
#include <cstdint>

// Problem constants
#define BS     32
#define VARNUM 16384
#define EMB    128
#define SEEDD  128
#define NH     16
#define HALFV  8192

// Tiling
#define NCHUNK3 16                 // K3: 16 chunks of 1024 v
#define CHUNKV3 (VARNUM / NCHUNK3) // 1024
#define VPT     4                  // v per thread in K3 (256 thr * 4 = 1024)
#define NCHUNK5 32                 // K5: 32 chunks of 512 v
#define CHUNKV5 (VARNUM / NCHUNK5) // 512
#define NPART   NCHUNK5            // one partial per K5 block (block-reduced)

// Workspace layout (bytes)
#define OFF_NORMQ 0
#define SZ_NORMQ  (BS*NH*EMB*4)               // 262144
#define OFF_LOSSP (OFF_NORMQ + SZ_NORMQ)
#define SZ_LOSSP  256
#define OFF_LPART (OFF_LOSSP + SZ_LOSSP)
#define SZ_LPART  (BS*NCHUNK3*NH*4)           // 32768
#define OFF_PBUF  (OFF_LPART + SZ_LPART)      // 295168 (16B aligned)
#define SZ_PBUF   (BS*VARNUM*NH*2)            // 16777216 (bf16 p)
#define OFF_PACC  (OFF_PBUF + SZ_PBUF)
#define SZ_PACC   ((size_t)BS*NPART*NH*EMB*4) // 8388608

static __device__ __forceinline__ uint16_t f2bf(float f) {
    uint32_t u = __float_as_uint(f);
    uint32_t r = (u + 0x7FFFu + ((u >> 16) & 1u)) >> 16;  // RTN-even
    return (uint16_t)r;
}
static __device__ __forceinline__ float bf2f(uint16_t s) {
    return __uint_as_float((uint32_t)s << 16);
}
static __device__ __forceinline__ float dot4(float4 a, float4 b) {
    return a.x*b.x + a.y*b.y + a.z*b.z + a.w*b.w;
}

// K1: norm_qs[b,h,e] = normalize_e(tanh(sum_s w_qs[h,e,s]*seed[b,s]))
__global__ __launch_bounds__(128) void k1_q(const float* __restrict__ seed,
                                            const float* __restrict__ wqs,
                                            float* __restrict__ normq) {
    const int bh = blockIdx.x;
    const int b = bh >> 4, h = bh & 15;
    const int e = threadIdx.x;
    __shared__ __align__(16) float s_seed[SEEDD];
    s_seed[e] = seed[b*SEEDD + e];
    __syncthreads();
    const float4* w4 = (const float4*)(wqs + ((size_t)(h*EMB + e))*SEEDD);
    const float4* s4 = (const float4*)s_seed;
    float acc = 0.f;
    #pragma unroll
    for (int j = 0; j < SEEDD/4; ++j) acc += dot4(w4[j], s4[j]);
    float t = tanhf(acc);
    float sq = t*t;
    #pragma unroll
    for (int off = 32; off; off >>= 1) sq += __shfl_xor(sq, off);
    __shared__ float s_part[2];
    if ((threadIdx.x & 63) == 0) s_part[threadIdx.x >> 6] = sq;
    __syncthreads();
    float tot = s_part[0] + s_part[1];
    normq[((size_t)b*NH + h)*EMB + e] = t * rsqrtf(tot);
}

// K2: per-batch loss partial: sum_{h,g} (q̂h·q̂g - I)^2
__global__ __launch_bounds__(256) void k2_loss(const float* __restrict__ normq,
                                               float* __restrict__ lossp) {
    const int b = blockIdx.x;
    const int h = threadIdx.x >> 4, g = threadIdx.x & 15;
    const float4* qh = (const float4*)(normq + ((size_t)b*NH + h)*EMB);
    const float4* qg = (const float4*)(normq + ((size_t)b*NH + g)*EMB);
    float d = 0.f;
    #pragma unroll
    for (int j = 0; j < EMB/4; ++j) d += dot4(qh[j], qg[j]);
    d -= (h == g) ? 1.f : 0.f;
    float sq = d*d;
    #pragma unroll
    for (int off = 32; off; off >>= 1) sq += __shfl_xor(sq, off);
    __shared__ float sp[4];
    if ((threadIdx.x & 63) == 0) sp[threadIdx.x >> 6] = sq;
    __syncthreads();
    if (threadIdx.x == 0) lossp[b] = sp[0] + sp[1] + sp[2] + sp[3];
}

// K3: p[b,v,h] = mask ? exp(cos(q̂h, e_v) - 1) : 0   (bf16), plus per-chunk sum_v p
__global__ __launch_bounds__(256) void k3_logits(const float* __restrict__ emb,
                                                 const int* __restrict__ mask,
                                                 const float* __restrict__ normq,
                                                 uint16_t* __restrict__ pbuf,
                                                 float* __restrict__ lpart) {
    const int chunk = blockIdx.x, b = blockIdx.y;
    const int tid = threadIdx.x;
    __shared__ __align__(16) float qs[NH*EMB];
    #pragma unroll
    for (int i = 0; i < (NH*EMB)/256; ++i) qs[tid + 256*i] = normq[(size_t)b*NH*EMB + tid + 256*i];
    __syncthreads();

    const int vbase = chunk * CHUNKV3;
    const float* embB = emb + (size_t)b*VARNUM*EMB;

    int mk[VPT], vv[VPT];
    const float4* ptr[VPT];
    #pragma unroll
    for (int k = 0; k < VPT; ++k) {
        vv[k] = vbase + k*256 + tid;
        mk[k] = mask[b*HALFV + (vv[k] & (HALFV-1))];
        // masked lanes read a dummy (hot) row: no divergence, ~half HBM traffic saved
        ptr[k] = (const float4*)(embB + (size_t)(mk[k] ? vv[k] : vbase)*EMB);
    }

    float s[VPT][NH], nsq[VPT];
    #pragma unroll
    for (int k = 0; k < VPT; ++k) {
        nsq[k] = 0.f;
        #pragma unroll
        for (int h = 0; h < NH; ++h) s[k][h] = 0.f;
    }

    const float4* q4 = (const float4*)qs;
    #pragma unroll 2
    for (int j = 0; j < EMB/4; ++j) {
        float4 ev[VPT];
        #pragma unroll
        for (int k = 0; k < VPT; ++k) ev[k] = ptr[k][j];
        #pragma unroll
        for (int k = 0; k < VPT; ++k) nsq[k] += dot4(ev[k], ev[k]);
        #pragma unroll
        for (int h = 0; h < NH; ++h) {
            float4 q = q4[h*(EMB/4) + j];   // LDS broadcast, amortized over VPT rows
            #pragma unroll
            for (int k = 0; k < VPT; ++k) s[k][h] += dot4(ev[k], q);
        }
    }

    float lsum[NH];
    #pragma unroll
    for (int h = 0; h < NH; ++h) lsum[h] = 0.f;

    #pragma unroll
    for (int k = 0; k < VPT; ++k) {
        float rn = rsqrtf(nsq[k]);
        uint32_t u[8];
        #pragma unroll
        for (int hp = 0; hp < 8; ++hp) {
            float p0 = 0.f, p1 = 0.f;
            if (mk[k]) {
                p0 = __expf(s[k][2*hp]   * rn - 1.f);  // |cos|<=1 => shift by fixed max 1
                p1 = __expf(s[k][2*hp+1] * rn - 1.f);
            }
            uint16_t b0 = f2bf(p0), b1 = f2bf(p1);
            u[hp] = (uint32_t)b0 | ((uint32_t)b1 << 16);
            lsum[2*hp]   += bf2f(b0);   // denominator uses the rounded p (consistency)
            lsum[2*hp+1] += bf2f(b1);
        }
        uint4* dst = (uint4*)(pbuf + ((size_t)b*VARNUM + vv[k])*NH);
        dst[0] = make_uint4(u[0], u[1], u[2], u[3]);
        dst[1] = make_uint4(u[4], u[5], u[6], u[7]);
    }

    #pragma unroll
    for (int h = 0; h < NH; ++h) {
        float v = lsum[h];
        #pragma unroll
        for (int off = 32; off; off >>= 1) v += __shfl_xor(v, off);
        lsum[h] = v;
    }
    __shared__ float lred[4][NH];
    if ((tid & 63) == 0) {
        #pragma unroll
        for (int h = 0; h < NH; ++h) lred[tid >> 6][h] = lsum[h];
    }
    __syncthreads();
    if (tid < NH) {
        float t = lred[0][tid] + lred[1][tid] + lred[2][tid] + lred[3][tid];
        lpart[((size_t)b*NCHUNK3 + chunk)*NH + tid] = t;
    }
}

// K5: partial acc[b,part,h,e] = sum_{v in part} p[v,h] * emb[v,e]; skips masked v (wave-uniform)
__global__ __launch_bounds__(256) void k5_pv(const float* __restrict__ emb,
                                             const uint16_t* __restrict__ pbuf,
                                             float* __restrict__ pacc) {
    const int chunk = blockIdx.x, b = blockIdx.y;
    const int w = threadIdx.x >> 6, lane = threadIdx.x & 63;
    const int v0 = chunk*CHUNKV5 + w*(CHUNKV5/4);
    const int vend = v0 + CHUNKV5/4;
    const float* embB = emb + (size_t)b*VARNUM*EMB + 2*lane;
    const uint4* pb = (const uint4*)(pbuf + (size_t)b*VARNUM*NH);

    float acc[NH][2];
    #pragma unroll
    for (int h = 0; h < NH; ++h) { acc[h][0] = 0.f; acc[h][1] = 0.f; }

    uint4 a[4], c[4];
    #pragma unroll
    for (int i = 0; i < 4; ++i) { a[i] = pb[2*(v0+i)]; c[i] = pb[2*(v0+i)+1]; }

    for (int vb = v0; vb < vend; vb += 4) {
        uint4 an[4], cn[4];
        #pragma unroll
        for (int i = 0; i < 4; ++i) { an[i] = make_uint4(0,0,0,0); cn[i] = make_uint4(0,0,0,0); }
        if (vb + 4 < vend) {
            #pragma unroll
            for (int i = 0; i < 4; ++i) { an[i] = pb[2*(vb+4+i)]; cn[i] = pb[2*(vb+4+i)+1]; }
        }
        #pragma unroll
        for (int i = 0; i < 4; ++i) {
            uint32_t any = a[i].x | a[i].y | a[i].z | a[i].w | c[i].x | c[i].y | c[i].z | c[i].w;
            if (any) {   // uniform across the wave (mask depends only on v)
                float2 ev = *(const float2*)(embB + (size_t)(vb + i)*EMB);
                float p[NH];
                p[0]  = __uint_as_float(a[i].x << 16); p[1]  = __uint_as_float(a[i].x & 0xFFFF0000u);
                p[2]  = __uint_as_float(a[i].y << 16); p[3]  = __uint_as_float(a[i].y & 0xFFFF0000u);
                p[4]  = __uint_as_float(a[i].z << 16); p[5]  = __uint_as_float(a[i].z & 0xFFFF0000u);
                p[6]  = __uint_as_float(a[i].w << 16); p[7]  = __uint_as_float(a[i].w & 0xFFFF0000u);
                p[8]  = __uint_as_float(c[i].x << 16); p[9]  = __uint_as_float(c[i].x & 0xFFFF0000u);
                p[10] = __uint_as_float(c[i].y << 16); p[11] = __uint_as_float(c[i].y & 0xFFFF0000u);
                p[12] = __uint_as_float(c[i].z << 16); p[13] = __uint_as_float(c[i].z & 0xFFFF0000u);
                p[14] = __uint_as_float(c[i].w << 16); p[15] = __uint_as_float(c[i].w & 0xFFFF0000u);
                #pragma unroll
                for (int h = 0; h < NH; ++h) {
                    acc[h][0] += p[h]*ev.x;
                    acc[h][1] += p[h]*ev.y;
                }
            }
        }
        #pragma unroll
        for (int i = 0; i < 4; ++i) { a[i] = an[i]; c[i] = cn[i]; }
    }

    // block-reduce the 4 waves' partials -> one partial per block
    __shared__ float red[256*32];
    float* slot = red + threadIdx.x*32;
    #pragma unroll
    for (int h = 0; h < NH; ++h) { slot[2*h] = acc[h][0]; slot[2*h+1] = acc[h][1]; }
    __syncthreads();
    if (w == 0) {
        #pragma unroll
        for (int h = 0; h < NH; ++h) {
            float s0 = red[(lane)*32 + 2*h]     + red[(64+lane)*32 + 2*h]
                     + red[(128+lane)*32 + 2*h] + red[(192+lane)*32 + 2*h];
            float s1 = red[(lane)*32 + 2*h+1]     + red[(64+lane)*32 + 2*h+1]
                     + red[(128+lane)*32 + 2*h+1] + red[(192+lane)*32 + 2*h+1];
            *(float2*)(pacc + ((((size_t)b*NPART + chunk)*NH + h)*EMB + 2*lane)) = make_float2(s0, s1);
        }
    }
}

// K6: rc[b,h,e] = sum_part acc / sum_chunk l
__global__ __launch_bounds__(128) void k6_out(const float* __restrict__ pacc,
                                              const float* __restrict__ lpart,
                                              float* __restrict__ out) {
    const int bh = blockIdx.x;
    const int b = bh >> 4, h = bh & 15;
    const int e = threadIdx.x;
    float L = 0.f;
    #pragma unroll
    for (int c = 0; c < NCHUNK3; ++c) L += lpart[((size_t)b*NCHUNK3 + c)*NH + h];
    float acc = 0.f;
    for (int k = 0; k < NPART; ++k)
        acc += pacc[(((size_t)b*NPART + k)*NH + h)*EMB + e];
    out[((size_t)b*NH + h)*EMB + e] = acc / L;
}

__global__ __launch_bounds__(64) void k_loss(const float* __restrict__ lossp,
                                             float* __restrict__ out) {
    const int l = threadIdx.x;
    float v = (l < BS) ? lossp[l] : 0.f;
    #pragma unroll
    for (int off = 32; off; off >>= 1) v += __shfl_xor(v, off);
    if (l == 0) out[BS*NH*EMB] = v / (float)BS;
}

extern "C" void kernel_launch(void* const* d_in, const int* in_sizes, int n_in,
                              void* d_out, int out_size, void* d_ws, size_t ws_size,
                              hipStream_t stream) {
    const float* seed = (const float*)d_in[0];
    const float* emb  = (const float*)d_in[1];
    const int*   mask = (const int*)d_in[2];
    const float* wqs  = (const float*)d_in[3];
    float* out = (float*)d_out;

    char* ws = (char*)d_ws;
    float*    normq = (float*)(ws + OFF_NORMQ);
    float*    lossp = (float*)(ws + OFF_LOSSP);
    float*    lpart = (float*)(ws + OFF_LPART);
    uint16_t* pbuf  = (uint16_t*)(ws + OFF_PBUF);
    float*    pacc  = (float*)(ws + OFF_PACC);

    k1_q<<<BS*NH, 128, 0, stream>>>(seed, wqs, normq);
    k2_loss<<<BS, 256, 0, stream>>>(normq, lossp);
    k3_logits<<<dim3(NCHUNK3, BS), 256, 0, stream>>>(emb, mask, normq, pbuf, lpart);
    k5_pv<<<dim3(NCHUNK5, BS), 256, 0, stream>>>(emb, pbuf, pacc);
    k6_out<<<BS*NH, 128, 0, stream>>>(pacc, lpart, out);
    k_loss<<<1, 64, 0, stream>>>(lossp, out);
}

// Round 2
// 73.145 us; speedup vs baseline: 2.2962x; 2.2962x over previous
//
#include <hip/hip_runtime.h>
#include <hip/hip_bf16.h>
#include <cstdint>

// Problem constants
#define BS     32
#define VARNUM 16384
#define EMB    128
#define SEEDD  128
#define NH     16
#define HALFV  8192

// Fused-kernel tiling
#define NCHUNK 64                  // blocks per batch
#define VT     (VARNUM / NCHUNK)   // 256 v per block
#define TV     64                  // v per tile
#define NTILE  (VT / TV)           // 4

// LDS strides (bytes)
#define EST 2080                   // E subtile stride: 64 rows * 32B + 32B pad (bank spread)
#define PST 144                    // p_lds row stride: 72 bf16 (16h x 64v padded)

// Workspace layout (bytes)
#define OFF_NORMQ 0
#define SZ_NORMQ  (BS*NH*EMB*4)                  // 256 KB
#define OFF_LOSSP (OFF_NORMQ + SZ_NORMQ)
#define SZ_LOSSP  256
#define OFF_LPART (OFF_LOSSP + SZ_LOSSP)
#define SZ_LPART  (BS*NCHUNK*NH*4)               // 128 KB
#define OFF_PACC  (OFF_LPART + SZ_LPART)
#define SZ_PACC   ((size_t)BS*NCHUNK*NH*EMB*4)   // 16.8 MB

typedef __attribute__((ext_vector_type(8))) short bf16x8;  // MFMA A/B frag (8 bf16)
typedef __attribute__((ext_vector_type(4))) float f32x4;   // MFMA C/D frag

static __device__ __forceinline__ uint16_t f2bf(float f) {
    uint32_t u = __float_as_uint(f);
    return (uint16_t)((u + 0x7FFFu + ((u >> 16) & 1u)) >> 16);  // RTN-even
}
static __device__ __forceinline__ float bf2f(uint16_t s) {
    return __uint_as_float((uint32_t)s << 16);
}
static __device__ __forceinline__ float dot4(float4 a, float4 b) {
    return a.x*b.x + a.y*b.y + a.z*b.z + a.w*b.w;
}

// K1: norm_qs[b,h,e] = normalize_e(tanh(sum_s w_qs[h,e,s]*seed[b,s]))
__global__ __launch_bounds__(128) void k1_q(const float* __restrict__ seed,
                                            const float* __restrict__ wqs,
                                            float* __restrict__ normq) {
    const int bh = blockIdx.x;
    const int b = bh >> 4, h = bh & 15;
    const int e = threadIdx.x;
    __shared__ __align__(16) float s_seed[SEEDD];
    s_seed[e] = seed[b*SEEDD + e];
    __syncthreads();
    const float4* w4 = (const float4*)(wqs + ((size_t)(h*EMB + e))*SEEDD);
    const float4* s4 = (const float4*)s_seed;
    float acc = 0.f;
    #pragma unroll
    for (int j = 0; j < SEEDD/4; ++j) acc += dot4(w4[j], s4[j]);
    float t = tanhf(acc);
    float sq = t*t;
    #pragma unroll
    for (int off = 32; off; off >>= 1) sq += __shfl_xor(sq, off);
    __shared__ float s_part[2];
    if ((threadIdx.x & 63) == 0) s_part[threadIdx.x >> 6] = sq;
    __syncthreads();
    float tot = s_part[0] + s_part[1];
    normq[((size_t)b*NH + h)*EMB + e] = t * rsqrtf(tot);
}

// K2: per-batch loss partial: sum_{h,g} (q̂h·q̂g - I)^2
__global__ __launch_bounds__(256) void k2_loss(const float* __restrict__ normq,
                                               float* __restrict__ lossp) {
    const int b = blockIdx.x;
    const int h = threadIdx.x >> 4, g = threadIdx.x & 15;
    const float4* qh = (const float4*)(normq + ((size_t)b*NH + h)*EMB);
    const float4* qg = (const float4*)(normq + ((size_t)b*NH + g)*EMB);
    float d = 0.f;
    #pragma unroll
    for (int j = 0; j < EMB/4; ++j) d += dot4(qh[j], qg[j]);
    d -= (h == g) ? 1.f : 0.f;
    float sq = d*d;
    #pragma unroll
    for (int off = 32; off; off >>= 1) sq += __shfl_xor(sq, off);
    __shared__ float sp[4];
    if ((threadIdx.x & 63) == 0) sp[threadIdx.x >> 6] = sq;
    __syncthreads();
    if (threadIdx.x == 0) lossp[b] = sp[0] + sp[1] + sp[2] + sp[3];
}

// Fused: per (b, chunk of 256 v): stage E tile (bf16, mask-redirected) -> MFMA logits
// (fixed-shift softmax exp(cos-1)) -> MFMA PV -> partial O + partial lsum.
__global__ __launch_bounds__(256) void k_fused(const float* __restrict__ emb,
                                               const int* __restrict__ mask,
                                               const float* __restrict__ normq,
                                               float* __restrict__ pacc,
                                               float* __restrict__ lpart) {
    const int chunk = blockIdx.x, b = blockIdx.y;
    const int tid = threadIdx.x;
    const int w   = tid >> 6;          // wave 0..3
    const int l   = tid & 63;
    const int lhi = l >> 4;            // 0..3
    const int llo = l & 15;            // 0..15

    // E: 8 subtiles [64 v][16 e] bf16, padded stride (row-major within subtile)
    __shared__ __align__(16) unsigned char Elds[8*EST];     // 16640 B
    __shared__ __align__(16) unsigned char Plds[16*PST];    // 2304 B: p[16 h][64 v pad 72]
    __shared__ __align__(16) float nsq[TV];                 // row norms (f32)
    __shared__ float lred[4][NH];

    // ---- Q fragments in registers: B[k=e][n=h], lane: h=llo, k=f*32+lhi*8+i ----
    bf16x8 qf[4];
    {
        const float* qrow = normq + ((size_t)b*NH + llo)*EMB;
        #pragma unroll
        for (int f = 0; f < 4; ++f) {
            const float4* qs = (const float4*)(qrow + f*32 + lhi*8);
            float4 a = qs[0], c = qs[1];
            bf16x8 t;
            t[0]=(short)f2bf(a.x); t[1]=(short)f2bf(a.y); t[2]=(short)f2bf(a.z); t[3]=(short)f2bf(a.w);
            t[4]=(short)f2bf(c.x); t[5]=(short)f2bf(c.y); t[6]=(short)f2bf(c.z); t[7]=(short)f2bf(c.w);
            qf[f] = t;
        }
    }

    f32x4 acc0 = {0.f,0.f,0.f,0.f};   // O[h=lhi*4+r][e=w*32+llo]
    f32x4 acc1 = {0.f,0.f,0.f,0.f};   // O[h=lhi*4+r][e=w*32+16+llo]
    float Lh = 0.f;                   // partial sum_v p for h=llo (this lane's rows)

    const float* embB  = emb + (size_t)b*VARNUM*EMB;
    const int*   maskB = mask + b*HALFV;
    const int    r0    = tid >> 4;    // staging row base (0..15)
    const int    cb    = tid & 15;    // staging col-block (8 floats each)

    for (int t = 0; t < NTILE; ++t) {
        const int vg0 = chunk*VT + t*TV;

        // ---- stage 64 rows f32->bf16 into LDS; compute row norms (f32) ----
        #pragma unroll
        for (int rep = 0; rep < 4; ++rep) {
            const int row = rep*16 + r0;
            const int vg  = vg0 + row;
            const int mk  = maskB[vg & (HALFV-1)];
            const float4* src = (const float4*)(embB + (size_t)(mk ? vg : vg0)*EMB + cb*8);
            float4 x0 = src[0], x1 = src[1];
            float sq = dot4(x0,x0) + dot4(x1,x1);
            sq += __shfl_xor(sq, 1); sq += __shfl_xor(sq, 2);
            sq += __shfl_xor(sq, 4); sq += __shfl_xor(sq, 8);
            if (cb == 0) nsq[row] = sq;
            uint32_t d0 = (uint32_t)f2bf(x0.x) | ((uint32_t)f2bf(x0.y) << 16);
            uint32_t d1 = (uint32_t)f2bf(x0.z) | ((uint32_t)f2bf(x0.w) << 16);
            uint32_t d2 = (uint32_t)f2bf(x1.x) | ((uint32_t)f2bf(x1.y) << 16);
            uint32_t d3 = (uint32_t)f2bf(x1.z) | ((uint32_t)f2bf(x1.w) << 16);
            *(uint4*)(Elds + (cb>>1)*EST + row*32 + (cb&1)*16) = make_uint4(d0,d1,d2,d3);
        }
        __syncthreads();

        // ---- logits: S[v=w*16+..][h] = E · Q^T  (A=E rows, B=Q frags) ----
        f32x4 s = {0.f,0.f,0.f,0.f};
        #pragma unroll
        for (int f = 0; f < 4; ++f) {
            const int eblk = 2*f + (lhi >> 1);
            bf16x8 a = *(const bf16x8*)(Elds + eblk*EST + (w*16 + llo)*32 + (lhi&1)*16);
            s = __builtin_amdgcn_mfma_f32_16x16x32_bf16(a, qf[f], s, 0, 0, 0);
        }
        // lane holds S[v = w*16 + lhi*4 + r][h = llo]
        f32x4 nn = *(const f32x4*)(&nsq[w*16 + lhi*4]);
        const int vout = vg0 + w*16 + lhi*4;
        uint16_t pb[4];
        #pragma unroll
        for (int r = 0; r < 4; ++r) {
            const int mk = maskB[(vout + r) & (HALFV-1)];
            float p = mk ? __expf(s[r]*rsqrtf(nn[r]) - 1.f) : 0.f;  // |cos|<=1: fixed shift
            pb[r] = f2bf(p);
            Lh += bf2f(pb[r]);   // denominator from the rounded p (consistency)
        }
        {
            unsigned char* pdst = Plds + llo*PST + (w*16 + lhi*4)*2;
            *(uint32_t*)(pdst)     = (uint32_t)pb[0] | ((uint32_t)pb[1] << 16);
            *(uint32_t*)(pdst + 4) = (uint32_t)pb[2] | ((uint32_t)pb[3] << 16);
        }
        __syncthreads();

        // ---- PV: O[h][e] += P^T-tile · E-tile  (A=P rows, B=E columns) ----
        #pragma unroll
        for (int kf = 0; kf < 2; ++kf) {
            bf16x8 pa = *(const bf16x8*)(Plds + llo*PST + (kf*32 + lhi*8)*2);
            #pragma unroll
            for (int et = 0; et < 2; ++et) {
                const unsigned char* base = Elds + (w*2 + et)*EST + llo*2;
                bf16x8 bb;
                #pragma unroll
                for (int i = 0; i < 8; ++i)
                    bb[i] = *(const short*)(base + (size_t)(kf*32 + lhi*8 + i)*32);
                if (et == 0) acc0 = __builtin_amdgcn_mfma_f32_16x16x32_bf16(pa, bb, acc0, 0, 0, 0);
                else         acc1 = __builtin_amdgcn_mfma_f32_16x16x32_bf16(pa, bb, acc1, 0, 0, 0);
            }
        }
        __syncthreads();   // before next tile's staging overwrites Elds/Plds
    }

    // ---- epilogue: partial O and partial lsum ----
    float* pout = pacc + (((size_t)b*NCHUNK + chunk)*NH)*EMB;
    #pragma unroll
    for (int r = 0; r < 4; ++r) {
        pout[(lhi*4 + r)*EMB + w*32 + llo]      = acc0[r];
        pout[(lhi*4 + r)*EMB + w*32 + 16 + llo] = acc1[r];
    }
    Lh += __shfl_xor(Lh, 16);
    Lh += __shfl_xor(Lh, 32);
    if (l < 16) lred[w][l] = Lh;
    __syncthreads();
    if (tid < 16)
        lpart[((size_t)b*NCHUNK + chunk)*NH + tid] =
            lred[0][tid] + lred[1][tid] + lred[2][tid] + lred[3][tid];
}

// K6: rc[b,h,e] = sum_chunk pacc / sum_chunk lpart
__global__ __launch_bounds__(128) void k6_out(const float* __restrict__ pacc,
                                              const float* __restrict__ lpart,
                                              float* __restrict__ out) {
    const int bh = blockIdx.x;
    const int b = bh >> 4, h = bh & 15;
    const int e = threadIdx.x;
    float L = 0.f;
    #pragma unroll
    for (int c = 0; c < NCHUNK; ++c) L += lpart[((size_t)b*NCHUNK + c)*NH + h];
    float acc = 0.f;
    for (int k = 0; k < NCHUNK; ++k)
        acc += pacc[(((size_t)b*NCHUNK + k)*NH + h)*EMB + e];
    out[((size_t)b*NH + h)*EMB + e] = acc / L;
}

__global__ __launch_bounds__(64) void k_loss(const float* __restrict__ lossp,
                                             float* __restrict__ out) {
    const int l = threadIdx.x;
    float v = (l < BS) ? lossp[l] : 0.f;
    #pragma unroll
    for (int off = 32; off; off >>= 1) v += __shfl_xor(v, off);
    if (l == 0) out[BS*NH*EMB] = v / (float)BS;
}

extern "C" void kernel_launch(void* const* d_in, const int* in_sizes, int n_in,
                              void* d_out, int out_size, void* d_ws, size_t ws_size,
                              hipStream_t stream) {
    const float* seed = (const float*)d_in[0];
    const float* emb  = (const float*)d_in[1];
    const int*   mask = (const int*)d_in[2];
    const float* wqs  = (const float*)d_in[3];
    float* out = (float*)d_out;

    char* ws = (char*)d_ws;
    float* normq = (float*)(ws + OFF_NORMQ);
    float* lossp = (float*)(ws + OFF_LOSSP);
    float* lpart = (float*)(ws + OFF_LPART);
    float* pacc  = (float*)(ws + OFF_PACC);

    k1_q<<<BS*NH, 128, 0, stream>>>(seed, wqs, normq);
    k2_loss<<<BS, 256, 0, stream>>>(normq, lossp);
    k_fused<<<dim3(NCHUNK, BS), 256, 0, stream>>>(emb, mask, normq, pacc, lpart);
    k6_out<<<BS*NH, 128, 0, stream>>>(pacc, lpart, out);
    k_loss<<<1, 64, 0, stream>>>(lossp, out);
}

// Round 6
// 62.854 us; speedup vs baseline: 2.6722x; 1.1637x over previous
//
#include <hip/hip_runtime.h>
#include <hip/hip_bf16.h>
#include <cstdint>

// Problem constants
#define BS     32
#define VARNUM 16384
#define EMB    128
#define SEEDD  128
#define NH     16
#define HALFV  8192

// Fused-kernel tiling
#define NCHUNK 32                  // blocks per batch
#define VT     (VARNUM / NCHUNK)   // 512 v per block
#define TV     64                  // v per tile
#define NTILE  (VT / TV)           // 8

// LDS strides (bytes)
#define EST 2080                   // E slab: [64 v][16 e] bf16 + 32B pad (R2-verified)
#define PST 144                    // p_lds row stride: 72 bf16 (16h x 64v padded)

// Workspace layout (bytes)
#define OFF_NORMQ 0
#define SZ_NORMQ  (BS*NH*EMB*4)                  // 256 KB
#define OFF_LOSSP (OFF_NORMQ + SZ_NORMQ)
#define SZ_LOSSP  256
#define OFF_LPART (OFF_LOSSP + SZ_LOSSP)
#define SZ_LPART  (BS*NCHUNK*NH*4)               // 64 KB
#define OFF_PACC  (OFF_LPART + SZ_LPART)
#define SZ_PACC   ((size_t)BS*NCHUNK*NH*EMB*4)   // 8.4 MB

typedef __attribute__((ext_vector_type(8))) short bf16x8;  // MFMA A/B frag (8 bf16)
typedef __attribute__((ext_vector_type(4))) float f32x4;   // MFMA C/D frag

static __device__ __forceinline__ uint16_t f2bf(float f) {
    uint32_t u = __float_as_uint(f);
    return (uint16_t)((u + 0x7FFFu + ((u >> 16) & 1u)) >> 16);  // RTN-even
}
static __device__ __forceinline__ uint32_t packbf(float a, float b) {
    __hip_bfloat162 h = __float22bfloat162_rn(make_float2(a, b));  // v_cvt_pk_bf16_f32
    uint32_t u;
    __builtin_memcpy(&u, &h, 4);
    return u;
}
static __device__ __forceinline__ float dot4(float4 a, float4 b) {
    return a.x*b.x + a.y*b.y + a.z*b.z + a.w*b.w;
}

// K1: norm_qs[b,h,e] = normalize_e(tanh(sum_s w_qs[h,e,s]*seed[b,s]))
__global__ __launch_bounds__(128) void k1_q(const float* __restrict__ seed,
                                            const float* __restrict__ wqs,
                                            float* __restrict__ normq) {
    const int bh = blockIdx.x;
    const int b = bh >> 4, h = bh & 15;
    const int e = threadIdx.x;
    __shared__ __align__(16) float s_seed[SEEDD];
    s_seed[e] = seed[b*SEEDD + e];
    __syncthreads();
    const float4* w4 = (const float4*)(wqs + ((size_t)(h*EMB + e))*SEEDD);
    const float4* s4 = (const float4*)s_seed;
    float acc = 0.f;
    #pragma unroll
    for (int j = 0; j < SEEDD/4; ++j) acc += dot4(w4[j], s4[j]);
    float t = tanhf(acc);
    float sq = t*t;
    #pragma unroll
    for (int off = 32; off; off >>= 1) sq += __shfl_xor(sq, off);
    __shared__ float s_part[2];
    if ((threadIdx.x & 63) == 0) s_part[threadIdx.x >> 6] = sq;
    __syncthreads();
    float tot = s_part[0] + s_part[1];
    normq[((size_t)b*NH + h)*EMB + e] = t * rsqrtf(tot);
}

// K2: per-batch loss partial: sum_{h,g} (q̂h·q̂g - I)^2
__global__ __launch_bounds__(256) void k2_loss(const float* __restrict__ normq,
                                               float* __restrict__ lossp) {
    const int b = blockIdx.x;
    const int h = threadIdx.x >> 4, g = threadIdx.x & 15;
    const float4* qh = (const float4*)(normq + ((size_t)b*NH + h)*EMB);
    const float4* qg = (const float4*)(normq + ((size_t)b*NH + g)*EMB);
    float d = 0.f;
    #pragma unroll
    for (int j = 0; j < EMB/4; ++j) d += dot4(qh[j], qg[j]);
    d -= (h == g) ? 1.f : 0.f;
    float sq = d*d;
    #pragma unroll
    for (int off = 32; off; off >>= 1) sq += __shfl_xor(sq, off);
    __shared__ float sp[4];
    if ((threadIdx.x & 63) == 0) sp[threadIdx.x >> 6] = sq;
    __syncthreads();
    if (threadIdx.x == 0) lossp[b] = sp[0] + sp[1] + sp[2] + sp[3];
}

// Fused: per (b, chunk of 512 v): stage E tile (bf16, mask-redirected) -> MFMA logits
// (fixed-shift softmax exp(cos-1)) -> MFMA PV (B via u16 gathers, R2-verified) -> partials.
__global__ __launch_bounds__(256) void k_fused(const float* __restrict__ emb,
                                               const int* __restrict__ mask,
                                               const float* __restrict__ normq,
                                               float* __restrict__ pacc,
                                               float* __restrict__ lpart) {
    const int chunk = blockIdx.x, b = blockIdx.y;
    const int tid = threadIdx.x;
    const int w   = tid >> 6;          // wave 0..3
    const int l   = tid & 63;
    const int lhi = l >> 4;            // 0..3
    const int llo = l & 15;            // 0..15

    __shared__ __align__(16) unsigned char Elds[8*EST];     // 16640 B
    __shared__ __align__(16) unsigned char Plds[16*PST];    // 2304 B: p[16 h][64 v pad 72]
    __shared__ __align__(16) float nsq[TV];                 // mk ? ||e||^2 : 0  (f32)
    __shared__ float lred[4][NH];

    // ---- Q fragments in registers: B[k=e][n=h], lane: h=llo, k=f*32+lhi*8+i ----
    bf16x8 qf[4];
    {
        const float* qrow = normq + ((size_t)b*NH + llo)*EMB;
        #pragma unroll
        for (int f = 0; f < 4; ++f) {
            const float4* qs = (const float4*)(qrow + f*32 + lhi*8);
            float4 a = qs[0], c = qs[1];
            bf16x8 t;
            t[0]=(short)f2bf(a.x); t[1]=(short)f2bf(a.y); t[2]=(short)f2bf(a.z); t[3]=(short)f2bf(a.w);
            t[4]=(short)f2bf(c.x); t[5]=(short)f2bf(c.y); t[6]=(short)f2bf(c.z); t[7]=(short)f2bf(c.w);
            qf[f] = t;
        }
    }

    f32x4 acc0 = {0.f,0.f,0.f,0.f};   // O[h=lhi*4+r][e=w*32+llo]
    f32x4 acc1 = {0.f,0.f,0.f,0.f};   // O[h=lhi*4+r][e=w*32+16+llo]
    float Lh = 0.f;                   // partial sum_v p for h=llo

    const float* embB  = emb + (size_t)b*VARNUM*EMB;
    const int*   maskB = mask + b*HALFV;
    const int    r0    = tid >> 4;    // staging row base (0..15)
    const int    cb    = tid & 15;    // staging col-block (8 floats each)

    for (int t = 0; t < NTILE; ++t) {
        const int vg0 = chunk*VT + t*TV;

        // ---- stage 64 rows f32->bf16 into LDS; masked-norm into nsq ----
        #pragma unroll
        for (int rep = 0; rep < 4; ++rep) {
            const int row = rep*16 + r0;
            const int vg  = vg0 + row;
            const int mk  = maskB[vg & (HALFV-1)];
            const float4* src = (const float4*)(embB + (size_t)(mk ? vg : vg0)*EMB + cb*8);
            float4 x0 = src[0], x1 = src[1];
            float sq = dot4(x0,x0) + dot4(x1,x1);
            sq += __shfl_xor(sq, 1); sq += __shfl_xor(sq, 2);
            sq += __shfl_xor(sq, 4); sq += __shfl_xor(sq, 8);
            if (cb == 0) nsq[row] = mk ? sq : 0.f;
            uint32_t d0 = packbf(x0.x, x0.y), d1 = packbf(x0.z, x0.w);
            uint32_t d2 = packbf(x1.x, x1.y), d3 = packbf(x1.z, x1.w);
            *(uint4*)(Elds + (cb>>1)*EST + row*32 + (cb&1)*16) = make_uint4(d0,d1,d2,d3);
        }
        __syncthreads();

        // ---- logits: S[v][h] = E · Q^T  (A=E rows via b128, B=Q regs) ----
        f32x4 s = {0.f,0.f,0.f,0.f};
        #pragma unroll
        for (int f = 0; f < 4; ++f) {
            const int eblk = 2*f + (lhi >> 1);
            bf16x8 a = *(const bf16x8*)(Elds + eblk*EST + (w*16 + llo)*32 + (lhi&1)*16);
            s = __builtin_amdgcn_mfma_f32_16x16x32_bf16(a, qf[f], s, 0, 0, 0);
        }
        // lane holds S[v = w*16 + lhi*4 + r][h = llo]
        f32x4 nn = *(const f32x4*)(&nsq[w*16 + lhi*4]);
        float p[4];
        #pragma unroll
        for (int r = 0; r < 4; ++r)
            p[r] = (nn[r] > 0.f) ? __expf(s[r]*rsqrtf(nn[r]) - 1.f) : 0.f;  // |cos|<=1
        uint32_t u0 = packbf(p[0], p[1]), u1 = packbf(p[2], p[3]);
        // denominator from the rounded p (consistency with PV)
        Lh += __uint_as_float(u0 << 16) + __uint_as_float(u0 & 0xFFFF0000u)
            + __uint_as_float(u1 << 16) + __uint_as_float(u1 & 0xFFFF0000u);
        {
            unsigned char* pdst = Plds + llo*PST + (w*16 + lhi*4)*2;
            *(uint32_t*)(pdst)     = u0;
            *(uint32_t*)(pdst + 4) = u1;
        }
        __syncthreads();

        // ---- PV: O[h][e] += P-tile · E-tile  (A=P via b128, B=E via u16 gathers) ----
        #pragma unroll
        for (int kf = 0; kf < 2; ++kf) {
            // A-frag layout: lane(llo,lhi) needs P[h=llo][v = kf*32 + lhi*8 + i]
            bf16x8 pa = *(const bf16x8*)(Plds + llo*PST + kf*64 + lhi*16);
            #pragma unroll
            for (int et = 0; et < 2; ++et) {
                const unsigned char* base = Elds + (w*2 + et)*EST + llo*2;
                bf16x8 bb;
                #pragma unroll
                for (int i = 0; i < 8; ++i)
                    bb[i] = *(const short*)(base + (size_t)(kf*32 + lhi*8 + i)*32);
                if (et == 0) acc0 = __builtin_amdgcn_mfma_f32_16x16x32_bf16(pa, bb, acc0, 0, 0, 0);
                else         acc1 = __builtin_amdgcn_mfma_f32_16x16x32_bf16(pa, bb, acc1, 0, 0, 0);
            }
        }
        __syncthreads();   // before next tile's staging overwrites Elds/Plds
    }

    // ---- epilogue: partial O and partial lsum ----
    float* pout = pacc + (((size_t)b*NCHUNK + chunk)*NH)*EMB;
    #pragma unroll
    for (int r = 0; r < 4; ++r) {
        pout[(lhi*4 + r)*EMB + w*32 + llo]      = acc0[r];
        pout[(lhi*4 + r)*EMB + w*32 + 16 + llo] = acc1[r];
    }
    Lh += __shfl_xor(Lh, 16);
    Lh += __shfl_xor(Lh, 32);
    if (l < 16) lred[w][l] = Lh;
    __syncthreads();
    if (tid < 16)
        lpart[((size_t)b*NCHUNK + chunk)*NH + tid] =
            lred[0][tid] + lred[1][tid] + lred[2][tid] + lred[3][tid];
}

// K6: rc[b,h,e] = sum_chunk pacc / sum_chunk lpart
__global__ __launch_bounds__(128) void k6_out(const float* __restrict__ pacc,
                                              const float* __restrict__ lpart,
                                              float* __restrict__ out) {
    const int bh = blockIdx.x;
    const int b = bh >> 4, h = bh & 15;
    const int e = threadIdx.x;
    float L = 0.f;
    #pragma unroll
    for (int c = 0; c < NCHUNK; ++c) L += lpart[((size_t)b*NCHUNK + c)*NH + h];
    float acc = 0.f;
    for (int k = 0; k < NCHUNK; ++k)
        acc += pacc[(((size_t)b*NCHUNK + k)*NH + h)*EMB + e];
    out[((size_t)b*NH + h)*EMB + e] = acc / L;
}

__global__ __launch_bounds__(64) void k_loss(const float* __restrict__ lossp,
                                             float* __restrict__ out) {
    const int l = threadIdx.x;
    float v = (l < BS) ? lossp[l] : 0.f;
    #pragma unroll
    for (int off = 32; off; off >>= 1) v += __shfl_xor(v, off);
    if (l == 0) out[BS*NH*EMB] = v / (float)BS;
}

extern "C" void kernel_launch(void* const* d_in, const int* in_sizes, int n_in,
                              void* d_out, int out_size, void* d_ws, size_t ws_size,
                              hipStream_t stream) {
    const float* seed = (const float*)d_in[0];
    const float* emb  = (const float*)d_in[1];
    const int*   mask = (const int*)d_in[2];
    const float* wqs  = (const float*)d_in[3];
    float* out = (float*)d_out;

    char* ws = (char*)d_ws;
    float* normq = (float*)(ws + OFF_NORMQ);
    float* lossp = (float*)(ws + OFF_LOSSP);
    float* lpart = (float*)(ws + OFF_LPART);
    float* pacc  = (float*)(ws + OFF_PACC);

    k1_q<<<BS*NH, 128, 0, stream>>>(seed, wqs, normq);
    k2_loss<<<BS, 256, 0, stream>>>(normq, lossp);
    k_fused<<<dim3(NCHUNK, BS), 256, 0, stream>>>(emb, mask, normq, pacc, lpart);
    k6_out<<<BS*NH, 128, 0, stream>>>(pacc, lpart, out);
    k_loss<<<1, 64, 0, stream>>>(lossp, out);
}

// Round 7
// 53.532 us; speedup vs baseline: 3.1375x; 1.1741x over previous
//
#include <hip/hip_runtime.h>
#include <hip/hip_bf16.h>
#include <cstdint>

// Problem constants
#define BS     32
#define VARNUM 16384
#define EMB    128
#define SEEDD  128
#define NH     16
#define HALFV  8192

// Fused-kernel tiling
#define NCHUNK 32                  // blocks per batch
#define VT     (VARNUM / NCHUNK)   // 512 v per block
#define TV     64                  // v per tile
#define NTILE  (VT / TV)           // 8

// LDS strides (bytes)
#define EST 2080                   // E slab: [64 v][16 e] bf16 + 32B pad (R2-verified)
#define PST 144                    // p_lds row stride: 72 bf16 (16h x 64v padded)

// Workspace layout (bytes)
#define OFF_NORMQ 0
#define SZ_NORMQ  (BS*NH*EMB*4)                  // 256 KB
#define OFF_LOSSP (OFF_NORMQ + SZ_NORMQ)
#define SZ_LOSSP  256
#define OFF_LPART (OFF_LOSSP + SZ_LOSSP)
#define SZ_LPART  (BS*NCHUNK*NH*4)               // 64 KB
#define OFF_PACC  (OFF_LPART + SZ_LPART)
#define SZ_PACC   ((size_t)BS*NCHUNK*NH*EMB*4)   // 8.4 MB

typedef __attribute__((ext_vector_type(8))) short bf16x8;  // MFMA A/B frag (8 bf16)
typedef __attribute__((ext_vector_type(4))) float f32x4;   // MFMA C/D frag

static __device__ __forceinline__ uint16_t f2bf(float f) {
    uint32_t u = __float_as_uint(f);
    return (uint16_t)((u + 0x7FFFu + ((u >> 16) & 1u)) >> 16);  // RTN-even
}
static __device__ __forceinline__ uint32_t packbf(float a, float b) {
    __hip_bfloat162 h = __float22bfloat162_rn(make_float2(a, b));  // v_cvt_pk_bf16_f32
    uint32_t u;
    __builtin_memcpy(&u, &h, 4);
    return u;
}
static __device__ __forceinline__ float dot4(float4 a, float4 b) {
    return a.x*b.x + a.y*b.y + a.z*b.z + a.w*b.w;
}

// K1: norm_qs[b,h,e] = normalize_e(tanh(sum_s w_qs[h,e,s]*seed[b,s]))
__global__ __launch_bounds__(128) void k1_q(const float* __restrict__ seed,
                                            const float* __restrict__ wqs,
                                            float* __restrict__ normq) {
    const int bh = blockIdx.x;
    const int b = bh >> 4, h = bh & 15;
    const int e = threadIdx.x;
    __shared__ __align__(16) float s_seed[SEEDD];
    s_seed[e] = seed[b*SEEDD + e];
    __syncthreads();
    const float4* w4 = (const float4*)(wqs + ((size_t)(h*EMB + e))*SEEDD);
    const float4* s4 = (const float4*)s_seed;
    float acc = 0.f;
    #pragma unroll
    for (int j = 0; j < SEEDD/4; ++j) acc += dot4(w4[j], s4[j]);
    float t = tanhf(acc);
    float sq = t*t;
    #pragma unroll
    for (int off = 32; off; off >>= 1) sq += __shfl_xor(sq, off);
    __shared__ float s_part[2];
    if ((threadIdx.x & 63) == 0) s_part[threadIdx.x >> 6] = sq;
    __syncthreads();
    float tot = s_part[0] + s_part[1];
    normq[((size_t)b*NH + h)*EMB + e] = t * rsqrtf(tot);
}

// K2: per-batch loss partial: sum_{h,g} (q̂h·q̂g - I)^2
__global__ __launch_bounds__(256) void k2_loss(const float* __restrict__ normq,
                                               float* __restrict__ lossp) {
    const int b = blockIdx.x;
    const int h = threadIdx.x >> 4, g = threadIdx.x & 15;
    const float4* qh = (const float4*)(normq + ((size_t)b*NH + h)*EMB);
    const float4* qg = (const float4*)(normq + ((size_t)b*NH + g)*EMB);
    float d = 0.f;
    #pragma unroll
    for (int j = 0; j < EMB/4; ++j) d += dot4(qh[j], qg[j]);
    d -= (h == g) ? 1.f : 0.f;
    float sq = d*d;
    #pragma unroll
    for (int off = 32; off; off >>= 1) sq += __shfl_xor(sq, off);
    __shared__ float sp[4];
    if ((threadIdx.x & 63) == 0) sp[threadIdx.x >> 6] = sq;
    __syncthreads();
    if (threadIdx.x == 0) lossp[b] = sp[0] + sp[1] + sp[2] + sp[3];
}

// Fused: per (b, chunk of 512 v): tile loop with register-prefetch of the NEXT
// tile's mask+emb (issued under current tile's compute), f32->bf16 staging,
// MFMA logits (fixed-shift softmax exp(cos-1)), MFMA PV, partial outputs.
__global__ __launch_bounds__(256, 4) void k_fused(const float* __restrict__ emb,
                                                  const int* __restrict__ mask,
                                                  const float* __restrict__ normq,
                                                  float* __restrict__ pacc,
                                                  float* __restrict__ lpart) {
    const int chunk = blockIdx.x, b = blockIdx.y;
    const int tid = threadIdx.x;
    const int w   = tid >> 6;          // wave 0..3
    const int l   = tid & 63;
    const int lhi = l >> 4;            // 0..3
    const int llo = l & 15;            // 0..15

    __shared__ __align__(16) unsigned char Elds[8*EST];     // 16640 B
    __shared__ __align__(16) unsigned char Plds[16*PST];    // 2304 B: p[16 h][64 v pad 72]
    __shared__ __align__(16) float nsq[TV];                 // mk ? ||e||^2 : 0  (f32)
    __shared__ float lred[4][NH];

    // ---- Q fragments in registers: B[k=e][n=h], lane: h=llo, k=f*32+lhi*8+i ----
    bf16x8 qf[4];
    {
        const float* qrow = normq + ((size_t)b*NH + llo)*EMB;
        #pragma unroll
        for (int f = 0; f < 4; ++f) {
            const float4* qs = (const float4*)(qrow + f*32 + lhi*8);
            float4 a = qs[0], c = qs[1];
            bf16x8 t;
            t[0]=(short)f2bf(a.x); t[1]=(short)f2bf(a.y); t[2]=(short)f2bf(a.z); t[3]=(short)f2bf(a.w);
            t[4]=(short)f2bf(c.x); t[5]=(short)f2bf(c.y); t[6]=(short)f2bf(c.z); t[7]=(short)f2bf(c.w);
            qf[f] = t;
        }
    }

    f32x4 acc0 = {0.f,0.f,0.f,0.f};   // O[h=lhi*4+r][e=w*32+llo]
    f32x4 acc1 = {0.f,0.f,0.f,0.f};   // O[h=lhi*4+r][e=w*32+16+llo]
    float Lh = 0.f;                   // partial sum_v p for h=llo

    const float* embB  = emb + (size_t)b*VARNUM*EMB;
    const int*   maskB = mask + b*HALFV;
    const int    r0    = tid >> 4;    // staging row base (0..15)
    const int    cb    = tid & 15;    // staging col-block (8 floats each)

    // ---- prologue: load tile 0 (mask then redirected emb) into prefetch regs ----
    int    mk[4];
    float4 pfa[4], pfb[4];
    {
        const int vg00 = chunk*VT;
        #pragma unroll
        for (int rep = 0; rep < 4; ++rep)
            mk[rep] = maskB[(vg00 + rep*16 + r0) & (HALFV-1)];
        #pragma unroll
        for (int rep = 0; rep < 4; ++rep) {
            const int vg = vg00 + rep*16 + r0;
            const float4* src = (const float4*)(embB + (size_t)(mk[rep] ? vg : vg00)*EMB + cb*8);
            pfa[rep] = src[0]; pfb[rep] = src[1];
        }
    }

    for (int t = 0; t < NTILE; ++t) {
        const int vg0  = chunk*VT + t*TV;
        const int vg0n = vg0 + TV;

        // prefetch NEXT tile's mask early (latency hidden under convert below)
        int mkn[4];
        if (t + 1 < NTILE) {
            #pragma unroll
            for (int rep = 0; rep < 4; ++rep)
                mkn[rep] = maskB[(vg0n + rep*16 + r0) & (HALFV-1)];
        }

        // ---- convert prefetched f32 -> bf16 into LDS; masked-norm into nsq ----
        #pragma unroll
        for (int rep = 0; rep < 4; ++rep) {
            const int row = rep*16 + r0;
            float4 x0 = pfa[rep], x1 = pfb[rep];
            float sq = dot4(x0,x0) + dot4(x1,x1);
            sq += __shfl_xor(sq, 1); sq += __shfl_xor(sq, 2);
            sq += __shfl_xor(sq, 4); sq += __shfl_xor(sq, 8);
            if (cb == 0) nsq[row] = mk[rep] ? sq : 0.f;
            uint32_t d0 = packbf(x0.x, x0.y), d1 = packbf(x0.z, x0.w);
            uint32_t d2 = packbf(x1.x, x1.y), d3 = packbf(x1.z, x1.w);
            *(uint4*)(Elds + (cb>>1)*EST + row*32 + (cb&1)*16) = make_uint4(d0,d1,d2,d3);
        }
        __syncthreads();

        // ---- issue NEXT tile's emb loads (in flight across QK+softmax+PV) ----
        if (t + 1 < NTILE) {
            #pragma unroll
            for (int rep = 0; rep < 4; ++rep) {
                const int vg = vg0n + rep*16 + r0;
                const float4* src = (const float4*)(embB + (size_t)(mkn[rep] ? vg : vg0n)*EMB + cb*8);
                pfa[rep] = src[0]; pfb[rep] = src[1];
                mk[rep]  = mkn[rep];
            }
        }

        // ---- logits: S[v][h] = E · Q^T  (A=E rows via b128, B=Q regs) ----
        f32x4 s = {0.f,0.f,0.f,0.f};
        #pragma unroll
        for (int f = 0; f < 4; ++f) {
            const int eblk = 2*f + (lhi >> 1);
            bf16x8 a = *(const bf16x8*)(Elds + eblk*EST + (w*16 + llo)*32 + (lhi&1)*16);
            s = __builtin_amdgcn_mfma_f32_16x16x32_bf16(a, qf[f], s, 0, 0, 0);
        }
        // lane holds S[v = w*16 + lhi*4 + r][h = llo]
        f32x4 nn = *(const f32x4*)(&nsq[w*16 + lhi*4]);
        float p[4];
        #pragma unroll
        for (int r = 0; r < 4; ++r)
            p[r] = (nn[r] > 0.f) ? __expf(s[r]*rsqrtf(nn[r]) - 1.f) : 0.f;  // |cos|<=1
        uint32_t u0 = packbf(p[0], p[1]), u1 = packbf(p[2], p[3]);
        // denominator from the rounded p (consistency with PV)
        Lh += __uint_as_float(u0 << 16) + __uint_as_float(u0 & 0xFFFF0000u)
            + __uint_as_float(u1 << 16) + __uint_as_float(u1 & 0xFFFF0000u);
        {
            unsigned char* pdst = Plds + llo*PST + (w*16 + lhi*4)*2;
            *(uint32_t*)(pdst)     = u0;
            *(uint32_t*)(pdst + 4) = u1;
        }
        __syncthreads();

        // ---- PV: O[h][e] += P-tile · E-tile  (A=P via b128, B=E via u16 gathers) ----
        #pragma unroll
        for (int kf = 0; kf < 2; ++kf) {
            // A-frag layout: lane(llo,lhi) needs P[h=llo][v = kf*32 + lhi*8 + i]
            bf16x8 pa = *(const bf16x8*)(Plds + llo*PST + kf*64 + lhi*16);
            #pragma unroll
            for (int et = 0; et < 2; ++et) {
                const unsigned char* base = Elds + (w*2 + et)*EST + llo*2;
                bf16x8 bb;
                #pragma unroll
                for (int i = 0; i < 8; ++i)
                    bb[i] = *(const short*)(base + (size_t)(kf*32 + lhi*8 + i)*32);
                if (et == 0) acc0 = __builtin_amdgcn_mfma_f32_16x16x32_bf16(pa, bb, acc0, 0, 0, 0);
                else         acc1 = __builtin_amdgcn_mfma_f32_16x16x32_bf16(pa, bb, acc1, 0, 0, 0);
            }
        }
        __syncthreads();   // before next tile's staging overwrites Elds/Plds
    }

    // ---- epilogue: partial O and partial lsum ----
    float* pout = pacc + (((size_t)b*NCHUNK + chunk)*NH)*EMB;
    #pragma unroll
    for (int r = 0; r < 4; ++r) {
        pout[(lhi*4 + r)*EMB + w*32 + llo]      = acc0[r];
        pout[(lhi*4 + r)*EMB + w*32 + 16 + llo] = acc1[r];
    }
    Lh += __shfl_xor(Lh, 16);
    Lh += __shfl_xor(Lh, 32);
    if (l < 16) lred[w][l] = Lh;
    __syncthreads();
    if (tid < 16)
        lpart[((size_t)b*NCHUNK + chunk)*NH + tid] =
            lred[0][tid] + lred[1][tid] + lred[2][tid] + lred[3][tid];
}

// K6: rc[b,h,e] = sum_chunk pacc / sum_chunk lpart
__global__ __launch_bounds__(128) void k6_out(const float* __restrict__ pacc,
                                              const float* __restrict__ lpart,
                                              float* __restrict__ out) {
    const int bh = blockIdx.x;
    const int b = bh >> 4, h = bh & 15;
    const int e = threadIdx.x;
    float L = 0.f;
    #pragma unroll
    for (int c = 0; c < NCHUNK; ++c) L += lpart[((size_t)b*NCHUNK + c)*NH + h];
    float acc = 0.f;
    for (int k = 0; k < NCHUNK; ++k)
        acc += pacc[(((size_t)b*NCHUNK + k)*NH + h)*EMB + e];
    out[((size_t)b*NH + h)*EMB + e] = acc / L;
}

__global__ __launch_bounds__(64) void k_loss(const float* __restrict__ lossp,
                                             float* __restrict__ out) {
    const int l = threadIdx.x;
    float v = (l < BS) ? lossp[l] : 0.f;
    #pragma unroll
    for (int off = 32; off; off >>= 1) v += __shfl_xor(v, off);
    if (l == 0) out[BS*NH*EMB] = v / (float)BS;
}

extern "C" void kernel_launch(void* const* d_in, const int* in_sizes, int n_in,
                              void* d_out, int out_size, void* d_ws, size_t ws_size,
                              hipStream_t stream) {
    const float* seed = (const float*)d_in[0];
    const float* emb  = (const float*)d_in[1];
    const int*   mask = (const int*)d_in[2];
    const float* wqs  = (const float*)d_in[3];
    float* out = (float*)d_out;

    char* ws = (char*)d_ws;
    float* normq = (float*)(ws + OFF_NORMQ);
    float* lossp = (float*)(ws + OFF_LOSSP);
    float* lpart = (float*)(ws + OFF_LPART);
    float* pacc  = (float*)(ws + OFF_PACC);

    k1_q<<<BS*NH, 128, 0, stream>>>(seed, wqs, normq);
    k2_loss<<<BS, 256, 0, stream>>>(normq, lossp);
    k_fused<<<dim3(NCHUNK, BS), 256, 0, stream>>>(emb, mask, normq, pacc, lpart);
    k6_out<<<BS*NH, 128, 0, stream>>>(pacc, lpart, out);
    k_loss<<<1, 64, 0, stream>>>(lossp, out);
}

// Round 8
// 51.125 us; speedup vs baseline: 3.2852x; 1.0471x over previous
//
#include <hip/hip_runtime.h>
#include <hip/hip_bf16.h>
#include <cstdint>

// Problem constants
#define BS     32
#define VARNUM 16384
#define EMB    128
#define SEEDD  128
#define NH     16
#define HALFV  8192

// Fused-kernel tiling
#define NCHUNK 32                  // blocks per batch
#define VT     (VARNUM / NCHUNK)   // 512 v per block
#define TV     64                  // v per tile
#define NTILE  (VT / TV)           // 8

// LDS strides (bytes)
#define EST 2080                   // E slab: [64 v][16 e] bf16 + 32B pad (R2-verified)
#define PST 144                    // p_lds row stride: 72 bf16 (16h x 64v padded)

// Workspace layout (bytes)
#define OFF_NORMQ 0
#define SZ_NORMQ  (BS*NH*EMB*4)                  // 256 KB
#define OFF_LOSSP (OFF_NORMQ + SZ_NORMQ)
#define SZ_LOSSP  256
#define OFF_LPART (OFF_LOSSP + SZ_LOSSP)
#define SZ_LPART  (BS*NCHUNK*NH*4)               // 64 KB
#define OFF_PACC  (OFF_LPART + SZ_LPART)
#define SZ_PACC   ((size_t)BS*NCHUNK*NH*EMB*4)   // 8.4 MB

typedef __attribute__((ext_vector_type(8))) short bf16x8;  // MFMA A/B frag (8 bf16)
typedef __attribute__((ext_vector_type(4))) float f32x4;   // MFMA C/D frag

// lgkm-only barrier: LDS producer/consumer ordering WITHOUT draining vmcnt —
// keeps prefetch global loads in flight across the barrier (T4 mechanism).
// __syncthreads() would emit s_waitcnt vmcnt(0) and kill the prefetch window.
#define BAR() do { \
    asm volatile("s_waitcnt lgkmcnt(0)" ::: "memory"); \
    __builtin_amdgcn_s_barrier(); \
} while (0)

static __device__ __forceinline__ uint16_t f2bf(float f) {
    uint32_t u = __float_as_uint(f);
    return (uint16_t)((u + 0x7FFFu + ((u >> 16) & 1u)) >> 16);  // RTN-even
}
static __device__ __forceinline__ uint32_t packbf(float a, float b) {
    __hip_bfloat162 h = __float22bfloat162_rn(make_float2(a, b));  // v_cvt_pk_bf16_f32
    uint32_t u;
    __builtin_memcpy(&u, &h, 4);
    return u;
}
static __device__ __forceinline__ float dot4(float4 a, float4 b) {
    return a.x*b.x + a.y*b.y + a.z*b.z + a.w*b.w;
}

// K1: norm_qs[b,h,e] = normalize_e(tanh(sum_s w_qs[h,e,s]*seed[b,s]))
__global__ __launch_bounds__(128) void k1_q(const float* __restrict__ seed,
                                            const float* __restrict__ wqs,
                                            float* __restrict__ normq) {
    const int bh = blockIdx.x;
    const int b = bh >> 4, h = bh & 15;
    const int e = threadIdx.x;
    __shared__ __align__(16) float s_seed[SEEDD];
    s_seed[e] = seed[b*SEEDD + e];
    __syncthreads();
    const float4* w4 = (const float4*)(wqs + ((size_t)(h*EMB + e))*SEEDD);
    const float4* s4 = (const float4*)s_seed;
    float acc = 0.f;
    #pragma unroll
    for (int j = 0; j < SEEDD/4; ++j) acc += dot4(w4[j], s4[j]);
    float t = tanhf(acc);
    float sq = t*t;
    #pragma unroll
    for (int off = 32; off; off >>= 1) sq += __shfl_xor(sq, off);
    __shared__ float s_part[2];
    if ((threadIdx.x & 63) == 0) s_part[threadIdx.x >> 6] = sq;
    __syncthreads();
    float tot = s_part[0] + s_part[1];
    normq[((size_t)b*NH + h)*EMB + e] = t * rsqrtf(tot);
}

// K2: per-batch loss partial: sum_{h,g} (q̂h·q̂g - I)^2
__global__ __launch_bounds__(256) void k2_loss(const float* __restrict__ normq,
                                               float* __restrict__ lossp) {
    const int b = blockIdx.x;
    const int h = threadIdx.x >> 4, g = threadIdx.x & 15;
    const float4* qh = (const float4*)(normq + ((size_t)b*NH + h)*EMB);
    const float4* qg = (const float4*)(normq + ((size_t)b*NH + g)*EMB);
    float d = 0.f;
    #pragma unroll
    for (int j = 0; j < EMB/4; ++j) d += dot4(qh[j], qg[j]);
    d -= (h == g) ? 1.f : 0.f;
    float sq = d*d;
    #pragma unroll
    for (int off = 32; off; off >>= 1) sq += __shfl_xor(sq, off);
    __shared__ float sp[4];
    if ((threadIdx.x & 63) == 0) sp[threadIdx.x >> 6] = sq;
    __syncthreads();
    if (threadIdx.x == 0) lossp[b] = sp[0] + sp[1] + sp[2] + sp[3];
}

// Fused: per (b, chunk of 512 v): double-buffered E tiles, 2 lgkm-only barriers
// per tile; register-prefetch of next tile's mask+emb rides across barriers.
__global__ __launch_bounds__(256, 4) void k_fused(const float* __restrict__ emb,
                                                  const int* __restrict__ mask,
                                                  const float* __restrict__ normq,
                                                  float* __restrict__ pacc,
                                                  float* __restrict__ lpart) {
    const int chunk = blockIdx.x, b = blockIdx.y;
    const int tid = threadIdx.x;
    const int w   = tid >> 6;          // wave 0..3
    const int l   = tid & 63;
    const int lhi = l >> 4;            // 0..3
    const int llo = l & 15;            // 0..15

    __shared__ __align__(16) unsigned char Elds[2][8*EST];  // 2 x 16640 B (dbuf)
    __shared__ __align__(16) unsigned char Plds[16*PST];    // 2304 B: p[16 h][64 v pad 72]
    __shared__ __align__(16) float nsq[TV];                 // mk ? ||e||^2 : 0  (f32)
    __shared__ float lred[4][NH];

    // ---- Q fragments in registers: B[k=e][n=h], lane: h=llo, k=f*32+lhi*8+i ----
    bf16x8 qf[4];
    {
        const float* qrow = normq + ((size_t)b*NH + llo)*EMB;
        #pragma unroll
        for (int f = 0; f < 4; ++f) {
            const float4* qs = (const float4*)(qrow + f*32 + lhi*8);
            float4 a = qs[0], c = qs[1];
            bf16x8 t;
            t[0]=(short)f2bf(a.x); t[1]=(short)f2bf(a.y); t[2]=(short)f2bf(a.z); t[3]=(short)f2bf(a.w);
            t[4]=(short)f2bf(c.x); t[5]=(short)f2bf(c.y); t[6]=(short)f2bf(c.z); t[7]=(short)f2bf(c.w);
            qf[f] = t;
        }
    }

    f32x4 acc0 = {0.f,0.f,0.f,0.f};   // O[h=lhi*4+r][e=w*32+llo]
    f32x4 acc1 = {0.f,0.f,0.f,0.f};   // O[h=lhi*4+r][e=w*32+16+llo]
    float Lh = 0.f;                   // partial sum_v p for h=llo

    const float* embB  = emb + (size_t)b*VARNUM*EMB;
    const int*   maskB = mask + b*HALFV;
    const int    r0    = tid >> 4;    // staging row base (0..15)
    const int    cb    = tid & 15;    // staging col-block (8 floats each)

    // ---- prologue: load tile 0 (mask then redirected emb) into prefetch regs ----
    int    mk[4];
    float4 pfa[4], pfb[4];
    {
        const int vg00 = chunk*VT;
        #pragma unroll
        for (int rep = 0; rep < 4; ++rep)
            mk[rep] = maskB[(vg00 + rep*16 + r0) & (HALFV-1)];
        #pragma unroll
        for (int rep = 0; rep < 4; ++rep) {
            const int vg = vg00 + rep*16 + r0;
            const float4* src = (const float4*)(embB + (size_t)(mk[rep] ? vg : vg00)*EMB + cb*8);
            pfa[rep] = src[0]; pfb[rep] = src[1];
        }
    }

    for (int t = 0; t < NTILE; ++t) {
        const int vg0n = chunk*VT + (t+1)*TV;
        unsigned char* Ebuf = Elds[t & 1];

        // prefetch NEXT tile's mask early (latency hidden under convert below)
        int mkn[4];
        if (t + 1 < NTILE) {
            #pragma unroll
            for (int rep = 0; rep < 4; ++rep)
                mkn[rep] = maskB[(vg0n + rep*16 + r0) & (HALFV-1)];
        }

        // ---- convert prefetched f32 -> bf16 into Ebuf; masked-norm into nsq ----
        #pragma unroll
        for (int rep = 0; rep < 4; ++rep) {
            const int row = rep*16 + r0;
            float4 x0 = pfa[rep], x1 = pfb[rep];
            float sq = dot4(x0,x0) + dot4(x1,x1);
            sq += __shfl_xor(sq, 1); sq += __shfl_xor(sq, 2);
            sq += __shfl_xor(sq, 4); sq += __shfl_xor(sq, 8);
            if (cb == 0) nsq[row] = mk[rep] ? sq : 0.f;
            uint32_t d0 = packbf(x0.x, x0.y), d1 = packbf(x0.z, x0.w);
            uint32_t d2 = packbf(x1.x, x1.y), d3 = packbf(x1.z, x1.w);
            *(uint4*)(Ebuf + (cb>>1)*EST + row*32 + (cb&1)*16) = make_uint4(d0,d1,d2,d3);
        }

        // ---- issue NEXT tile's emb loads (stay in flight across BOTH barriers) ----
        if (t + 1 < NTILE) {
            #pragma unroll
            for (int rep = 0; rep < 4; ++rep) {
                const int vg = vg0n + rep*16 + r0;
                const float4* src = (const float4*)(embB + (size_t)(mkn[rep] ? vg : vg0n)*EMB + cb*8);
                pfa[rep] = src[0]; pfb[rep] = src[1];
                mk[rep]  = mkn[rep];
            }
        }
        BAR();   // sync1: stage-writes -> QK-reads; also guards Plds overwrite below

        // ---- logits: S[v][h] = E · Q^T  (A=E rows via b128, B=Q regs) ----
        f32x4 s = {0.f,0.f,0.f,0.f};
        #pragma unroll
        for (int f = 0; f < 4; ++f) {
            const int eblk = 2*f + (lhi >> 1);
            bf16x8 a = *(const bf16x8*)(Ebuf + eblk*EST + (w*16 + llo)*32 + (lhi&1)*16);
            s = __builtin_amdgcn_mfma_f32_16x16x32_bf16(a, qf[f], s, 0, 0, 0);
        }
        // lane holds S[v = w*16 + lhi*4 + r][h = llo]
        f32x4 nn = *(const f32x4*)(&nsq[w*16 + lhi*4]);
        float p[4];
        #pragma unroll
        for (int r = 0; r < 4; ++r)
            p[r] = (nn[r] > 0.f) ? __expf(s[r]*rsqrtf(nn[r]) - 1.f) : 0.f;  // |cos|<=1
        uint32_t u0 = packbf(p[0], p[1]), u1 = packbf(p[2], p[3]);
        // denominator from the rounded p (consistency with PV)
        Lh += __uint_as_float(u0 << 16) + __uint_as_float(u0 & 0xFFFF0000u)
            + __uint_as_float(u1 << 16) + __uint_as_float(u1 & 0xFFFF0000u);
        {
            unsigned char* pdst = Plds + llo*PST + (w*16 + lhi*4)*2;
            *(uint32_t*)(pdst)     = u0;
            *(uint32_t*)(pdst + 4) = u1;
        }
        BAR();   // sync2: P-writes -> PV-reads; nsq reads done before next convert

        // ---- PV: O[h][e] += P-tile · E-tile  (A=P via b128, B=E via u16 gathers) ----
        // no barrier after PV: next convert writes the OTHER E buffer (dbuf)
        #pragma unroll
        for (int kf = 0; kf < 2; ++kf) {
            // A-frag layout: lane(llo,lhi) needs P[h=llo][v = kf*32 + lhi*8 + i]
            bf16x8 pa = *(const bf16x8*)(Plds + llo*PST + kf*64 + lhi*16);
            #pragma unroll
            for (int et = 0; et < 2; ++et) {
                const unsigned char* base = Ebuf + (w*2 + et)*EST + llo*2;
                bf16x8 bb;
                #pragma unroll
                for (int i = 0; i < 8; ++i)
                    bb[i] = *(const short*)(base + (size_t)(kf*32 + lhi*8 + i)*32);
                if (et == 0) acc0 = __builtin_amdgcn_mfma_f32_16x16x32_bf16(pa, bb, acc0, 0, 0, 0);
                else         acc1 = __builtin_amdgcn_mfma_f32_16x16x32_bf16(pa, bb, acc1, 0, 0, 0);
            }
        }
    }

    // ---- epilogue: partial O and partial lsum ----
    float* pout = pacc + (((size_t)b*NCHUNK + chunk)*NH)*EMB;
    #pragma unroll
    for (int r = 0; r < 4; ++r) {
        pout[(lhi*4 + r)*EMB + w*32 + llo]      = acc0[r];
        pout[(lhi*4 + r)*EMB + w*32 + 16 + llo] = acc1[r];
    }
    Lh += __shfl_xor(Lh, 16);
    Lh += __shfl_xor(Lh, 32);
    if (l < 16) lred[w][l] = Lh;
    BAR();
    if (tid < 16)
        lpart[((size_t)b*NCHUNK + chunk)*NH + tid] =
            lred[0][tid] + lred[1][tid] + lred[2][tid] + lred[3][tid];
}

// K6: rc[b,h,e] = sum_chunk pacc / sum_chunk lpart; block 0 also writes the loss
__global__ __launch_bounds__(128) void k6_out(const float* __restrict__ pacc,
                                              const float* __restrict__ lpart,
                                              const float* __restrict__ lossp,
                                              float* __restrict__ out) {
    const int bh = blockIdx.x;
    const int b = bh >> 4, h = bh & 15;
    const int e = threadIdx.x;
    float L = 0.f;
    #pragma unroll
    for (int c = 0; c < NCHUNK; ++c) L += lpart[((size_t)b*NCHUNK + c)*NH + h];
    float acc = 0.f;
    for (int k = 0; k < NCHUNK; ++k)
        acc += pacc[(((size_t)b*NCHUNK + k)*NH + h)*EMB + e];
    out[((size_t)b*NH + h)*EMB + e] = acc / L;
    if (bh == 0 && e < 64) {
        float v = (e < BS) ? lossp[e] : 0.f;
        #pragma unroll
        for (int off = 32; off; off >>= 1) v += __shfl_xor(v, off);
        if (e == 0) out[BS*NH*EMB] = v / (float)BS;
    }
}

extern "C" void kernel_launch(void* const* d_in, const int* in_sizes, int n_in,
                              void* d_out, int out_size, void* d_ws, size_t ws_size,
                              hipStream_t stream) {
    const float* seed = (const float*)d_in[0];
    const float* emb  = (const float*)d_in[1];
    const int*   mask = (const int*)d_in[2];
    const float* wqs  = (const float*)d_in[3];
    float* out = (float*)d_out;

    char* ws = (char*)d_ws;
    float* normq = (float*)(ws + OFF_NORMQ);
    float* lossp = (float*)(ws + OFF_LOSSP);
    float* lpart = (float*)(ws + OFF_LPART);
    float* pacc  = (float*)(ws + OFF_PACC);

    k1_q<<<BS*NH, 128, 0, stream>>>(seed, wqs, normq);
    k2_loss<<<BS, 256, 0, stream>>>(normq, lossp);
    k_fused<<<dim3(NCHUNK, BS), 256, 0, stream>>>(emb, mask, normq, pacc, lpart);
    k6_out<<<BS*NH, 128, 0, stream>>>(pacc, lpart, lossp, out);
}